// Round 3
// baseline (3213.036 us; speedup 1.0000x reference)
//
#include <hip/hip_runtime.h>
#include <hip/hip_cooperative_groups.h>

namespace cg = cooperative_groups;

#define N_NEUR 4096
#define B_SZ   64
#define T_STEPS 128
#define N_CLS  10

typedef double d4v __attribute__((ext_vector_type(4)));
typedef float  f4v __attribute__((ext_vector_type(4)));
typedef short  s8v __attribute__((ext_vector_type(8)));

// =====================================================================================
// bf16 3-split path.
// cur[n][b] = sum_m (W1+W2+W3)[n][m] * s[m][b], s in {0,1}, Wi = bf16 mantissa slices of
// f32 W (exact: W = W1+W2+W3). Products are exact in bf16 MFMA; only f32 accumulation
// rounds (~6e-7 after 16-way k-split + f64 cross-wave combine) — below reference noise.
// =====================================================================================

// exact 3-way bf16 split by mantissa truncation
__device__ inline void split3(float w, unsigned short& o1, unsigned short& o2, unsigned short& o3) {
    unsigned u1 = __float_as_uint(w);
    float w1 = __uint_as_float(u1 & 0xFFFF0000u);
    float r1 = w - w1;                      // exact (low mantissa bits)
    unsigned u2 = __float_as_uint(r1);
    float w2 = __uint_as_float(u2 & 0xFFFF0000u);
    float r2 = r1 - w2;                     // exact, <=8 significant bits
    o1 = (unsigned short)(u1 >> 16);
    o2 = (unsigned short)(u2 >> 16);
    o3 = (unsigned short)(__float_as_uint(r2) >> 16);   // exact truncation
}

// candidate k-orders for the 8 bf16 elements of an A/B fragment of mfma_f32_16x16x32_bf16
// map==0: two stacked K=16 halves: k = (e>>2)*16 + khi*4 + (e&3)
// map==1: contiguous 8:            k = khi*8 + e
__device__ inline int korder2(int map, int khi, int e) {
    return map ? ((khi << 3) | e)
               : (((e >> 2) << 4) | (khi << 2) | (e & 3));
}

// spike (m,b) -> index into B-fragment-ordered buffer (ushort units)
__device__ inline size_t sfrag_idx(int m, int b, int bm) {
    int kt = m >> 5, kl = m & 31, bt = b >> 4, c = b & 15;
    int khi, e;
    if (bm) { khi = kl >> 3; e = kl & 7; }
    else    { khi = (kl >> 2) & 3; e = (kl & 3) | (((kl >> 4) & 1) << 2); }
    return ((size_t)(kt * 4 + bt) * 64 + (khi << 4) + c) * 8 + e;
}

// ---------------- layout probe for bf16 MFMA: combo[1] = am | bm<<1 | dmap<<2 ----------------
__global__ void kernProbe2(int* __restrict__ combo_out) {
    int l = threadIdx.x;
    int khi = l >> 4, c = l & 15;
    int best = -1;
    for (int cb = 0; cb < 8; ++cb) {
        int am = cb & 1, bm = (cb >> 1) & 1, dmap = (cb >> 2) & 1;
        s8v av, bv;
        #pragma unroll
        for (int e = 0; e < 8; ++e) {
            int ka = korder2(am, khi, e);
            int kb = korder2(bm, khi, e);
            float aval = ldexpf((float)(c + 1), ka - 16);
            float bval = ldexpf((float)(2 * c + 1), -kb);
            av[e] = (short)(__float_as_uint(aval) >> 16);
            bv[e] = (short)(__float_as_uint(bval) >> 16);
        }
        f4v d = {0.f, 0.f, 0.f, 0.f};
        d = __builtin_amdgcn_mfma_f32_16x16x32_bf16(av, bv, d, 0, 0, 0);
        bool ok = true;
        #pragma unroll
        for (int r = 0; r < 4; ++r) {
            int q = (l >> 4) * 4 + r;
            int di = dmap ? c : q;
            int dj = dmap ? q : c;
            float expect = (float)((di + 1) * (2 * dj + 1)) * (32.0f / 65536.0f);
            ok = ok && (d[r] == expect);
        }
        unsigned long long m = __ballot(ok);
        if (m == ~0ull && best < 0) best = cb;
    }
    if (l == 0) combo_out[1] = (best < 0) ? 0 : best;
}

// ---------------- pack W into 3 bf16 A-fragment planes ----------------
// Wf3 layout (ushort units): frag(nt,kt,split) at ((nt*128+kt)*3+split)*512 + lane*8
__global__ __launch_bounds__(256) void kernP2(const float* __restrict__ W,
                                              unsigned short* __restrict__ Wf,
                                              const int* __restrict__ combo_p) {
    const int am = combo_p[1] & 1;
    const int nt = blockIdx.x;                 // 0..255
    const int lane = threadIdx.x & 63, wv = threadIdx.x >> 6;
    const int khi = lane >> 4, ai = lane & 15;
    const float* wrow = W + (size_t)(nt * 16 + ai) * N_NEUR;
    for (int kt = wv; kt < 128; kt += 4) {
        const int kb = kt * 32;
        float4 lo, hi;
        if (am) {
            lo = *(const float4*)(wrow + kb + khi * 8);
            hi = *(const float4*)(wrow + kb + khi * 8 + 4);
        } else {
            lo = *(const float4*)(wrow + kb + khi * 4);
            hi = *(const float4*)(wrow + kb + 16 + khi * 4);
        }
        float v[8] = {lo.x, lo.y, lo.z, lo.w, hi.x, hi.y, hi.z, hi.w};
        unsigned short s1[8], s2[8], s3[8];
        #pragma unroll
        for (int e = 0; e < 8; ++e) split3(v[e], s1[e], s2[e], s3[e]);
        size_t base = (((size_t)nt * 128 + kt) * 3) * 512 + (size_t)lane * 8;
        #pragma unroll
        for (int e = 0; e < 8; ++e) {
            Wf[base + e]        = s1[e];
            Wf[base + 512 + e]  = s2[e];
            Wf[base + 1024 + e] = s3[e];
        }
    }
}

// ---------------- t=0 init (bf16 path) ----------------
__global__ __launch_bounds__(256) void kernI2(const float* __restrict__ x,
                                              const float* __restrict__ Win,
                                              double* __restrict__ vr,
                                              unsigned short* __restrict__ sf,
                                              float* __restrict__ sT,
                                              const int* __restrict__ combo_p) {
    const int bm = (combo_p[1] >> 1) & 1;
    int idx = blockIdx.x * 256 + threadIdx.x;
    int b = idx & 63, n = idx >> 6;
    double v = (double)x[b * T_STEPS] * (double)Win[n];
    bool sp = (v >= 1.0);
    vr[idx] = sp ? 0.0 : v;
    sT[idx] = sp ? 1.0f : 0.0f;
    sf[sfrag_idx(n, b, bm)] = sp ? (unsigned short)0x3F80 : (unsigned short)0;
}

// ---------------- persistent coop loop: 256 blocks x 1024 threads, balanced ----------------
// Every block: 16-row n-stripe GEMM (16 waves = 16-way k-split of 256 k) + LIF, plus a
// quarter-k classifier partial for batch bid>>2 (atomicAdd into Pcur), plus (blocks<64)
// the vc LIF update for step t-2 from Pprev (completed last iteration).
__global__ __launch_bounds__(1024, 4) void kernLoop2(const unsigned short* __restrict__ Wf,
                                                     unsigned short* __restrict__ sf0,
                                                     unsigned short* __restrict__ sf1,
                                                     const float* __restrict__ x,
                                                     const float* __restrict__ Win,
                                                     double* __restrict__ vr,
                                                     float* __restrict__ sTa,
                                                     float* __restrict__ sTb,
                                                     const float* __restrict__ Wout,
                                                     double* __restrict__ vc,
                                                     double* __restrict__ counts,
                                                     double* __restrict__ P0,
                                                     double* __restrict__ P1,
                                                     const int* __restrict__ combo_p) {
    __shared__ double lbuf[8][1024];
    __shared__ double red[16][N_CLS];
    cg::grid_group grid = cg::this_grid();
    const int bid = blockIdx.x, tid = threadIdx.x;
    const int wave = tid >> 6, lane = tid & 63;
    const int combo = combo_p[1];
    const int bm = (combo >> 1) & 1, dmap = (combo >> 2) & 1;

    for (int t = 1; t < T_STEPS; ++t) {
        const unsigned short* sfp = (t & 1) ? sf0 : sf1;
        unsigned short*       sfc = (t & 1) ? sf1 : sf0;
        float*       sTc = (t & 1) ? sTb : sTa;
        const float* sTp = (t & 1) ? sTa : sTb;
        double* Pcur  = (t & 1) ? P1 : P0;
        double* Pprev = (t & 1) ? P0 : P1;

        // ---- GEMM: wave = k-sixteenth (256 k = 8 kf of 32) ----
        f4v acc[4][3];
        #pragma unroll
        for (int i = 0; i < 4; ++i)
            #pragma unroll
            for (int j = 0; j < 3; ++j)
                acc[i][j] = (f4v){0.f, 0.f, 0.f, 0.f};

        const unsigned short* ap = Wf  + (((size_t)bid * 128 + (size_t)wave * 8) * 3) * 512 + (size_t)lane * 8;
        const unsigned short* bp = sfp + ((size_t)wave * 8 * 4) * 512 + (size_t)lane * 8;

        #pragma unroll 2
        for (int kf = 0; kf < 8; ++kf) {
            s8v afr[3], bfr[4];
            #pragma unroll
            for (int s = 0; s < 3; ++s) afr[s] = *(const s8v*)(ap + s * 512);
            #pragma unroll
            for (int bt = 0; bt < 4; ++bt) bfr[bt] = *(const s8v*)(bp + bt * 512);
            #pragma unroll
            for (int bt = 0; bt < 4; ++bt) {
                acc[bt][0] = __builtin_amdgcn_mfma_f32_16x16x32_bf16(afr[0], bfr[bt], acc[bt][0], 0, 0, 0);
                acc[bt][1] = __builtin_amdgcn_mfma_f32_16x16x32_bf16(afr[1], bfr[bt], acc[bt][1], 0, 0, 0);
                acc[bt][2] = __builtin_amdgcn_mfma_f32_16x16x32_bf16(afr[2], bfr[bt], acc[bt][2], 0, 0, 0);
            }
            ap += 1536;
            bp += 2048;
        }

        // per-wave f64 combine of splits, then two-phase 16->8 cross-wave reduce in LDS
        double vals[4][4];
        int idxs[4][4];
        #pragma unroll
        for (int bt = 0; bt < 4; ++bt) {
            #pragma unroll
            for (int r = 0; r < 4; ++r) {
                vals[bt][r] = (double)acc[bt][0][r] + (double)acc[bt][1][r] + (double)acc[bt][2][r];
                int q = (lane >> 4) * 4 + r;
                int di = dmap ? (lane & 15) : q;
                int dj = dmap ? q : (lane & 15);
                idxs[bt][r] = di * 64 + bt * 16 + dj;
            }
        }
        if (wave < 8) {
            #pragma unroll
            for (int bt = 0; bt < 4; ++bt)
                #pragma unroll
                for (int r = 0; r < 4; ++r)
                    lbuf[wave][idxs[bt][r]] = vals[bt][r];
        }
        __syncthreads();
        if (wave >= 8) {
            #pragma unroll
            for (int bt = 0; bt < 4; ++bt)
                #pragma unroll
                for (int r = 0; r < 4; ++r)
                    lbuf[wave - 8][idxs[bt][r]] += vals[bt][r];
        }
        __syncthreads();

        // ---- reservoir LIF (one output per thread) ----
        {
            int n = bid * 16 + (tid >> 6), b = tid & 63;
            size_t gidx = (size_t)n * 64 + b;
            double cur = lbuf[0][tid] + lbuf[1][tid] + lbuf[2][tid] + lbuf[3][tid]
                       + lbuf[4][tid] + lbuf[5][tid] + lbuf[6][tid] + lbuf[7][tid]
                       + (double)x[b * T_STEPS + t] * (double)Win[n];
            double v = 0.9 * vr[gidx] + cur;
            bool sp = (v >= 1.0);
            vr[gidx] = sp ? 0.0 : v;
            sTc[gidx] = sp ? 1.0f : 0.0f;
            sfc[sfrag_idx(n, b, bm)] = sp ? (unsigned short)0x3F80 : (unsigned short)0;
        }

        // ---- classifier partial for s_{t-1}: batch bid>>2, m-range (bid&3)*1024 ----
        {
            int b2 = bid >> 2;
            int m = ((bid & 3) << 10) + tid;
            float s = sTp[(size_t)m * B_SZ + b2];
            double part[N_CLS];
            if (s != 0.0f) {
                #pragma unroll
                for (int c = 0; c < N_CLS; ++c)
                    part[c] = (double)Wout[c * N_NEUR + m];
            } else {
                #pragma unroll
                for (int c = 0; c < N_CLS; ++c) part[c] = 0.0;
            }
            #pragma unroll
            for (int c = 0; c < N_CLS; ++c) {
                double v = part[c];
                for (int off = 32; off > 0; off >>= 1)
                    v += __shfl_down(v, off, 64);
                if (lane == 0) red[wave][c] = v;
            }
            __syncthreads();
            if (tid < N_CLS) {
                double tot = 0.0;
                #pragma unroll
                for (int wv = 0; wv < 16; ++wv) tot += red[wv][tid];
                atomicAdd(&Pcur[b2 * N_CLS + tid], tot);
            }
        }

        // ---- classifier LIF for s_{t-2} from Pprev (completed last iteration) ----
        if (bid < B_SZ && t >= 2 && tid < N_CLS) {
            double tot = Pprev[bid * N_CLS + tid];
            double v = 0.9 * vc[bid * N_CLS + tid] + tot;
            bool sp = (v >= 1.0);
            vc[bid * N_CLS + tid] = sp ? 0.0 : v;
            if (sp) counts[bid * N_CLS + tid] += 1.0;
            Pprev[bid * N_CLS + tid] = 0.0;     // ready for reuse as Pcur next iteration
        }

        __threadfence();
        grid.sync();
    }
}

// ---------------- epilogue: vc update for s_126 (from Pp) then s_127 (direct dot) ----------------
__global__ __launch_bounds__(256) void kernC2(const float* __restrict__ sT,
                                              const float* __restrict__ Wout,
                                              double* __restrict__ vc,
                                              double* __restrict__ counts,
                                              const double* __restrict__ Pp) {
    int b = blockIdx.x;
    int tid = threadIdx.x;
    if (tid < N_CLS) {
        double v = 0.9 * vc[b * N_CLS + tid] + Pp[b * N_CLS + tid];
        bool sp = (v >= 1.0);
        vc[b * N_CLS + tid] = sp ? 0.0 : v;
        if (sp) counts[b * N_CLS + tid] += 1.0;
    }
    double part[N_CLS];
    #pragma unroll
    for (int c = 0; c < N_CLS; ++c) part[c] = 0.0;
    for (int m = tid; m < N_NEUR; m += 256) {
        double s = (double)sT[(size_t)m * B_SZ + b];
        #pragma unroll
        for (int c = 0; c < N_CLS; ++c)
            part[c] = fma(s, (double)Wout[c * N_NEUR + m], part[c]);
    }
    __shared__ double red[4][N_CLS];
    int lane = tid & 63, wv = tid >> 6;
    #pragma unroll
    for (int c = 0; c < N_CLS; ++c) {
        double v = part[c];
        for (int off = 32; off > 0; off >>= 1)
            v += __shfl_down(v, off, 64);
        if (lane == 0) red[wv][c] = v;
    }
    __syncthreads();
    if (tid < N_CLS) {
        double tot = red[0][tid] + red[1][tid] + red[2][tid] + red[3][tid];
        double v = 0.9 * vc[b * N_CLS + tid] + tot;
        bool sp = (v >= 1.0);
        vc[b * N_CLS + tid] = sp ? 0.0 : v;
        if (sp) counts[b * N_CLS + tid] += 1.0;
    }
}

// ---------------- per-step fallback (round-2 verified geometry: 320 x 512) ----------------
__device__ __forceinline__ void step_body(int bid, int tid,
                                          double (*lbuf)[1024], double (*red)[N_CLS],
                                          const unsigned short* __restrict__ Wf,
                                          const unsigned short* __restrict__ sfp,
                                          const float* __restrict__ x,
                                          const float* __restrict__ Win,
                                          double* __restrict__ vr,
                                          unsigned short* __restrict__ sfc,
                                          float* __restrict__ sTc,
                                          const float* __restrict__ sTp,
                                          const float* __restrict__ Wout,
                                          double* __restrict__ vc,
                                          double* __restrict__ counts,
                                          int combo, int t) {
    const int wave = tid >> 6, lane = tid & 63;

    if (bid >= 256) {
        const int b = bid - 256;
        double part[N_CLS];
        #pragma unroll
        for (int c = 0; c < N_CLS; ++c) part[c] = 0.0;
        for (int m = tid; m < N_NEUR; m += 512) {
            double s = (double)sTp[(size_t)m * B_SZ + b];
            #pragma unroll
            for (int c = 0; c < N_CLS; ++c)
                part[c] = fma(s, (double)Wout[c * N_NEUR + m], part[c]);
        }
        #pragma unroll
        for (int c = 0; c < N_CLS; ++c) {
            double v = part[c];
            for (int off = 32; off > 0; off >>= 1)
                v += __shfl_down(v, off, 64);
            if (lane == 0) red[wave][c] = v;
        }
        __syncthreads();
        if (tid < N_CLS) {
            double tot = 0.0;
            #pragma unroll
            for (int wv = 0; wv < 8; ++wv) tot += red[wv][tid];
            double v = 0.9 * vc[b * N_CLS + tid] + tot;
            bool sp = (v >= 1.0);
            vc[b * N_CLS + tid] = sp ? 0.0 : v;
            if (sp) counts[b * N_CLS + tid] += 1.0;
        }
        return;
    }

    const int bm = (combo >> 1) & 1, dmap = (combo >> 2) & 1;
    const int nt = bid;
    const int kq = wave;

    f4v acc[4][3];
    #pragma unroll
    for (int i = 0; i < 4; ++i)
        #pragma unroll
        for (int j = 0; j < 3; ++j)
            acc[i][j] = (f4v){0.f, 0.f, 0.f, 0.f};

    const unsigned short* ap = Wf  + (((size_t)nt * 128 + (size_t)kq * 16) * 3) * 512 + (size_t)lane * 8;
    const unsigned short* bp = sfp + ((size_t)kq * 16 * 4) * 512 + (size_t)lane * 8;

    #pragma unroll 2
    for (int kf = 0; kf < 16; ++kf) {
        s8v afr[3], bfr[4];
        #pragma unroll
        for (int s = 0; s < 3; ++s) afr[s] = *(const s8v*)(ap + s * 512);
        #pragma unroll
        for (int bt = 0; bt < 4; ++bt) bfr[bt] = *(const s8v*)(bp + bt * 512);
        #pragma unroll
        for (int bt = 0; bt < 4; ++bt) {
            acc[bt][0] = __builtin_amdgcn_mfma_f32_16x16x32_bf16(afr[0], bfr[bt], acc[bt][0], 0, 0, 0);
            acc[bt][1] = __builtin_amdgcn_mfma_f32_16x16x32_bf16(afr[1], bfr[bt], acc[bt][1], 0, 0, 0);
            acc[bt][2] = __builtin_amdgcn_mfma_f32_16x16x32_bf16(afr[2], bfr[bt], acc[bt][2], 0, 0, 0);
        }
        ap += 1536;
        bp += 2048;
    }

    double vals[4][4];
    int idxs[4][4];
    #pragma unroll
    for (int bt = 0; bt < 4; ++bt) {
        #pragma unroll
        for (int r = 0; r < 4; ++r) {
            vals[bt][r] = (double)acc[bt][0][r] + (double)acc[bt][1][r] + (double)acc[bt][2][r];
            int q = (lane >> 4) * 4 + r;
            int di = dmap ? (lane & 15) : q;
            int dj = dmap ? q : (lane & 15);
            idxs[bt][r] = di * 64 + bt * 16 + dj;
        }
    }
    if (kq < 4) {
        #pragma unroll
        for (int bt = 0; bt < 4; ++bt)
            #pragma unroll
            for (int r = 0; r < 4; ++r)
                lbuf[kq][idxs[bt][r]] = vals[bt][r];
    }
    __syncthreads();
    if (kq >= 4) {
        #pragma unroll
        for (int bt = 0; bt < 4; ++bt)
            #pragma unroll
            for (int r = 0; r < 4; ++r)
                lbuf[kq - 4][idxs[bt][r]] += vals[bt][r];
    }
    __syncthreads();

    for (int i = tid; i < 16 * 64; i += 512) {
        int n = nt * 16 + (i >> 6), b = i & 63;
        size_t gidx = (size_t)n * 64 + b;
        double cur = lbuf[0][i] + lbuf[1][i] + lbuf[2][i] + lbuf[3][i]
                   + (double)x[b * T_STEPS + t] * (double)Win[n];
        double v = 0.9 * vr[gidx] + cur;
        bool sp = (v >= 1.0);
        vr[gidx] = sp ? 0.0 : v;
        sTc[gidx] = sp ? 1.0f : 0.0f;
        sfc[sfrag_idx(n, b, bm)] = sp ? (unsigned short)0x3F80 : (unsigned short)0;
    }
}

__global__ __launch_bounds__(512, 4) void kernAB3(const unsigned short* __restrict__ Wf,
                                                  const unsigned short* __restrict__ sfp,
                                                  const float* __restrict__ x,
                                                  const float* __restrict__ Win,
                                                  double* __restrict__ vr,
                                                  unsigned short* __restrict__ sfc,
                                                  float* __restrict__ sTc,
                                                  const float* __restrict__ sTp,
                                                  const float* __restrict__ Wout,
                                                  double* __restrict__ vc,
                                                  double* __restrict__ counts,
                                                  const int* __restrict__ combo_p,
                                                  int t) {
    __shared__ double lbuf[4][1024];
    __shared__ double red[8][N_CLS];
    step_body(blockIdx.x, threadIdx.x, lbuf, red, Wf, sfp, x, Win, vr, sfc, sTc, sTp,
              Wout, vc, counts, combo_p[1], t);
}

// =====================================================================================
// f64 fallback path (verified) — used when ws too small for the bf16 planes.
// =====================================================================================

__global__ void kernProbe(int* __restrict__ combo_out) {
    int l = threadIdx.x;
    int best = -1;
    for (int c = 0; c < 16; ++c) {
        int amap = c & 1, bmap = (c >> 1) & 1, dmap = (c >> 2) & 3;
        int ai = amap ? (l >> 2) : (l & 15);
        int ak = amap ? (l & 3)  : (l >> 4);
        int bk = bmap ? (l & 3)  : (l >> 4);
        int bj = bmap ? (l >> 2) : (l & 15);
        double a = (double)(ai * 4 + ak + 1);
        double b = (double)(bk * 16 + bj + 1);
        d4v d = {0.0, 0.0, 0.0, 0.0};
        d = __builtin_amdgcn_mfma_f64_16x16x4f64(a, b, d, 0, 0, 0);
        bool ok = true;
        #pragma unroll
        for (int r = 0; r < 4; ++r) {
            int di, dj;
            if      (dmap == 0) { di = 4 * (l >> 4) + r; dj = l & 15; }
            else if (dmap == 1) { di = l & 15; dj = 4 * (l >> 4) + r; }
            else if (dmap == 2) { di = (l >> 4) + 4 * r; dj = l & 15; }
            else                { di = l & 15; dj = (l >> 4) + 4 * r; }
            double ref = 0.0;
            for (int k = 0; k < 4; ++k)
                ref += (double)(di * 4 + k + 1) * (double)(k * 16 + dj + 1);
            ok = ok && (d[r] == ref);
        }
        unsigned long long m = __ballot(ok);
        if (m == ~0ull && best < 0) best = c;
    }
    if (l == 0) combo_out[0] = (best < 0) ? 0 : best;
}

__global__ __launch_bounds__(256) void kernP(const float* __restrict__ W,
                                             float* __restrict__ Wf,
                                             const int* __restrict__ combo_p) {
    const int combo = combo_p[0];
    const int amap = combo & 1;
    const int stripe = blockIdx.x;
    const int lane = threadIdx.x & 63;
    const int ai = amap ? (lane >> 2) : (lane & 15);
    const int ak = amap ? (lane & 3)  : (lane >> 4);
    const size_t nrow = (size_t)(stripe * 16 + ai) * N_NEUR;
    for (int q = threadIdx.x >> 6; q < 1024; q += 4)
        Wf[((size_t)stripe * 1024 + q) * 64 + lane] = W[nrow + 4 * q + ak];
}

__global__ __launch_bounds__(256) void kernI(const float* __restrict__ x,
                                             const float* __restrict__ Win,
                                             double* __restrict__ vr,
                                             float* __restrict__ sf,
                                             float* __restrict__ sT) {
    int idx = blockIdx.x * 256 + threadIdx.x;
    int b = idx & 63, n = idx >> 6;
    double v = (double)x[b * T_STEPS] * (double)Win[n];
    bool sp = (v >= 1.0);
    vr[idx] = sp ? 0.0 : v;
    float s = sp ? 1.0f : 0.0f;
    sT[idx] = s;
    sf[(size_t)(((n >> 2) * 4 + (b >> 4)) * 64) + (n & 3) * 16 + (b & 15)] = s;
}

template<bool USEWF>
__global__ __launch_bounds__(1024) void kernAB(const float* __restrict__ Wsrc,
                                               const float* __restrict__ sfp,
                                               const float* __restrict__ x,
                                               const float* __restrict__ Win,
                                               double* __restrict__ vr,
                                               float* __restrict__ sfc,
                                               float* __restrict__ sTc,
                                               const float* __restrict__ sTp,
                                               const float* __restrict__ Wout,
                                               double* __restrict__ vc,
                                               double* __restrict__ counts,
                                               const int* __restrict__ combo_p,
                                               int t) {
    __shared__ double lbuf[4][16 * 64];
    __shared__ double red[16][N_CLS];
    const int tid  = threadIdx.x;
    const int wave = tid >> 6, lane = tid & 63;

    if (blockIdx.x >= 256) {
        const int b = blockIdx.x - 256;
        double part[N_CLS];
        #pragma unroll
        for (int c = 0; c < N_CLS; ++c) part[c] = 0.0;
        for (int m = tid; m < N_NEUR; m += 1024) {
            double s = (double)sTp[(size_t)m * B_SZ + b];
            #pragma unroll
            for (int c = 0; c < N_CLS; ++c)
                part[c] = fma(s, (double)Wout[c * N_NEUR + m], part[c]);
        }
        #pragma unroll
        for (int c = 0; c < N_CLS; ++c) {
            double v = part[c];
            for (int off = 32; off > 0; off >>= 1)
                v += __shfl_down(v, off, 64);
            if (lane == 0) red[wave][c] = v;
        }
        __syncthreads();
        if (tid < N_CLS) {
            double tot = 0.0;
            #pragma unroll
            for (int wv = 0; wv < 16; ++wv) tot += red[wv][tid];
            double v = 0.9 * vc[b * N_CLS + tid] + tot;
            bool sp = (v >= 1.0);
            vc[b * N_CLS + tid] = sp ? 0.0 : v;
            if (sp) counts[b * N_CLS + tid] += 1.0;
        }
        return;
    }

    const int wb = wave & 3, wq = wave >> 2;
    const int gn0 = blockIdx.x * 16;
    const int combo = combo_p[0];
    const int amap = combo & 1, bmap = (combo >> 1) & 1, dmap = (combo >> 2) & 3;
    const int bk = bmap ? (lane & 3)  : (lane >> 4);
    const int bj = bmap ? (lane >> 2) : (lane & 15);

    d4v acc = {0.0, 0.0, 0.0, 0.0};
    const int q0 = wq * 256;
    const float* bp = sfp + (size_t)(q0 * 4 + wb) * 64 + bk * 16 + bj;

    if (USEWF) {
        const float* ap = Wsrc + ((size_t)blockIdx.x * 1024 + q0) * 64 + lane;
        for (int blk = 0; blk < 64; ++blk) {
            #pragma unroll
            for (int u = 0; u < 4; ++u) {
                double a  = (double)ap[u * 64];
                double bv = (double)bp[u * 256];
                acc = __builtin_amdgcn_mfma_f64_16x16x4f64(a, bv, acc, 0, 0, 0);
            }
            ap += 256;
            bp += 1024;
        }
    } else {
        const int ai = amap ? (lane >> 2) : (lane & 15);
        const int ak = amap ? (lane & 3)  : (lane >> 4);
        #pragma unroll 4
        for (int q = 0; q < 256; ++q) {
            double a  = (double)Wsrc[(size_t)(gn0 + ai) * N_NEUR + 4 * (q0 + q) + ak];
            double bv = (double)bp[(size_t)q * 256];
            acc = __builtin_amdgcn_mfma_f64_16x16x4f64(a, bv, acc, 0, 0, 0);
        }
    }

    {
        const int jb = 16 * wb;
        #pragma unroll
        for (int r = 0; r < 4; ++r) {
            int di, dj;
            if      (dmap == 0) { di = 4 * (lane >> 4) + r; dj = lane & 15; }
            else if (dmap == 1) { di = lane & 15; dj = 4 * (lane >> 4) + r; }
            else if (dmap == 2) { di = (lane >> 4) + 4 * r; dj = lane & 15; }
            else                { di = lane & 15; dj = (lane >> 4) + 4 * r; }
            lbuf[wq][di * 64 + jb + dj] = acc[r];
        }
    }
    __syncthreads();

    int nl = tid >> 6, b = tid & 63;
    int n = gn0 + nl;
    size_t gidx = (size_t)n * 64 + b;
    double cur = lbuf[0][tid] + lbuf[1][tid] + lbuf[2][tid] + lbuf[3][tid]
               + (double)x[b * T_STEPS + t] * (double)Win[n];
    double v = 0.9 * vr[gidx] + cur;
    bool sp = (v >= 1.0);
    vr[gidx] = sp ? 0.0 : v;
    float s = sp ? 1.0f : 0.0f;
    sTc[gidx] = s;
    sfc[(size_t)(((n >> 2) * 4 + (b >> 4)) * 64) + (n & 3) * 16 + (b & 15)] = s;
}

// ---------------- standalone classifier (final step, fallback paths) ----------------
__global__ __launch_bounds__(256) void kernC(const float* __restrict__ sT,
                                             const float* __restrict__ Wout,
                                             double* __restrict__ vc,
                                             double* __restrict__ counts) {
    int b = blockIdx.x;
    int tid = threadIdx.x;
    double part[N_CLS];
    #pragma unroll
    for (int c = 0; c < N_CLS; ++c) part[c] = 0.0;
    for (int m = tid; m < N_NEUR; m += 256) {
        double s = (double)sT[(size_t)m * B_SZ + b];
        #pragma unroll
        for (int c = 0; c < N_CLS; ++c)
            part[c] = fma(s, (double)Wout[c * N_NEUR + m], part[c]);
    }
    __shared__ double red[4][N_CLS];
    int lane = tid & 63, wv = tid >> 6;
    #pragma unroll
    for (int c = 0; c < N_CLS; ++c) {
        double v = part[c];
        for (int off = 32; off > 0; off >>= 1)
            v += __shfl_down(v, off, 64);
        if (lane == 0) red[wv][c] = v;
    }
    __syncthreads();
    if (tid < N_CLS) {
        double tot = red[0][tid] + red[1][tid] + red[2][tid] + red[3][tid];
        double v = 0.9 * vc[b * N_CLS + tid] + tot;
        bool sp = (v >= 1.0);
        vc[b * N_CLS + tid] = sp ? 0.0 : v;
        if (sp) counts[b * N_CLS + tid] += 1.0;
    }
}

__global__ void kernD(const double* __restrict__ counts, float* __restrict__ out) {
    int i = blockIdx.x * blockDim.x + threadIdx.x;
    if (i < B_SZ * N_CLS) out[i] = (float)counts[i];
}

extern "C" void kernel_launch(void* const* d_in, const int* in_sizes, int n_in,
                              void* d_out, int out_size, void* d_ws, size_t ws_size,
                              hipStream_t stream) {
    const float* x    = (const float*)d_in[0];
    const float* Win  = (const float*)d_in[1];
    const float* Wres = (const float*)d_in[2];
    const float* Wout = (const float*)d_in[3];
    float* out = (float*)d_out;

    const size_t NB = (size_t)B_SZ * N_NEUR;
    char* w = (char*)d_ws;
    double* vr     = (double*)w;  w += NB * sizeof(double);
    float*  sTa    = (float*)w;   w += NB * sizeof(float);
    float*  sTb    = (float*)w;   w += NB * sizeof(float);
    float*  sf0    = (float*)w;   w += NB * sizeof(float);   // bf16 path uses first half as ushort
    float*  sf1    = (float*)w;   w += NB * sizeof(float);
    double* vc     = (double*)w;  w += (size_t)B_SZ * N_CLS * sizeof(double);
    double* counts = (double*)w;  w += (size_t)B_SZ * N_CLS * sizeof(double);
    double* P0     = (double*)w;  w += (size_t)B_SZ * N_CLS * sizeof(double);
    double* P1     = (double*)w;  w += (size_t)B_SZ * N_CLS * sizeof(double);
    int*    combo  = (int*)w;     w += 256;
    float*  Wf     = (float*)w;   // f64 path: 64 MB packed W; bf16 path: 96 MB 3-split planes

    size_t fixed = (size_t)(w - (char*)d_ws);
    bool use_bf16 = (ws_size >= fixed + 3ull * N_NEUR * N_NEUR * sizeof(unsigned short));
    bool use_wf   = (ws_size >= fixed + (size_t)N_NEUR * N_NEUR * sizeof(float));

    hipMemsetAsync(vc, 0, 4ull * B_SZ * N_CLS * sizeof(double), stream);   // vc, counts, P0, P1

    if (use_bf16) {
        unsigned short* Wf3  = (unsigned short*)Wf;
        unsigned short* sf0u = (unsigned short*)sf0;
        unsigned short* sf1u = (unsigned short*)sf1;
        kernProbe2<<<dim3(1), 64, 0, stream>>>(combo);
        kernP2<<<dim3(256), 256, 0, stream>>>(Wres, Wf3, combo);
        kernI2<<<dim3(NB / 256), 256, 0, stream>>>(x, Win, vr, sf0u, sTa, combo);

        int maxb = 0;
        hipError_t occ_err = hipOccupancyMaxActiveBlocksPerMultiprocessor(&maxb, kernLoop2, 1024, 0);
        bool coop = (occ_err == hipSuccess) && (maxb >= 1);

        if (coop) {
            void* kargs[] = {(void*)&Wf3, (void*)&sf0u, (void*)&sf1u, (void*)&x, (void*)&Win,
                             (void*)&vr, (void*)&sTa, (void*)&sTb, (void*)&Wout, (void*)&vc,
                             (void*)&counts, (void*)&P0, (void*)&P1, (void*)&combo};
            hipError_t le = hipLaunchCooperativeKernel((const void*)kernLoop2, dim3(256), dim3(1024),
                                                       kargs, 0, stream);
            coop = (le == hipSuccess);
        }
        if (coop) {
            kernC2<<<dim3(B_SZ), 256, 0, stream>>>(sTb, Wout, vc, counts, P1);
        } else {
            for (int t = 1; t < T_STEPS; ++t) {
                const unsigned short* sfp = (t & 1) ? sf0u : sf1u;
                unsigned short*       sfc = (t & 1) ? sf1u : sf0u;
                float*       sTc = (t & 1) ? sTb : sTa;
                const float* sTp = (t & 1) ? sTa : sTb;
                kernAB3<<<dim3(320), 512, 0, stream>>>(Wf3, sfp, x, Win, vr, sfc, sTc, sTp,
                                                       Wout, vc, counts, combo, t);
            }
            kernC<<<dim3(B_SZ), 256, 0, stream>>>(sTb, Wout, vc, counts);
        }
        kernD<<<dim3(3), 256, 0, stream>>>(counts, out);
        return;
    }

    kernProbe<<<dim3(1), 64, 0, stream>>>(combo);
    if (use_wf)
        kernP<<<dim3(256), 256, 0, stream>>>(Wres, Wf, combo);

    kernI<<<dim3(NB / 256), 256, 0, stream>>>(x, Win, vr, sf0, sTa);
    for (int t = 1; t < T_STEPS; ++t) {
        const float* sfp = (t & 1) ? sf0 : sf1;
        float*       sfc = (t & 1) ? sf1 : sf0;
        float*       sTc = (t & 1) ? sTb : sTa;
        const float* sTp = (t & 1) ? sTa : sTb;
        if (use_wf)
            kernAB<true><<<dim3(320), 1024, 0, stream>>>(Wf, sfp, x, Win, vr, sfc, sTc, sTp,
                                                         Wout, vc, counts, combo, t);
        else
            kernAB<false><<<dim3(320), 1024, 0, stream>>>(Wres, sfp, x, Win, vr, sfc, sTc, sTp,
                                                          Wout, vc, counts, combo, t);
    }
    kernC<<<dim3(B_SZ), 256, 0, stream>>>(sTb, Wout, vc, counts);
    kernD<<<dim3(3), 256, 0, stream>>>(counts, out);
}

// Round 4
// 3118.101 us; speedup vs baseline: 1.0304x; 1.0304x over previous
//
#include <hip/hip_runtime.h>
#include <hip/hip_cooperative_groups.h>

namespace cg = cooperative_groups;

#define N_NEUR 4096
#define B_SZ   64
#define T_STEPS 128
#define N_CLS  10

typedef double d4v __attribute__((ext_vector_type(4)));
typedef float  f4v __attribute__((ext_vector_type(4)));
typedef int    i4v __attribute__((ext_vector_type(4)));
typedef long   l2v __attribute__((ext_vector_type(2)));

// =====================================================================================
// i8 3-digit fixed-point path.
// q[n][m] = rint(W[n][m] * 2^s)  (|q| <= 8.3e6, s dynamic), split q = d2*2^16+d1*2^8+d0
// into signed i8 digits (exact identity). cur = (P2*2^16+P1*2^8+P0) * 2^-s where
// Pi = sum_m di[n][m]*spike[m][b] via i32 MFMA — integer accumulation is EXACT; the only
// error is quantization (<=5e-9/weight), far below the verified bf16-3split noise.
// =====================================================================================

// k-order candidates for the 8 i8 elements of an A/B fragment of mfma_i32_16x16x32_i8
// map==0: two stacked K=16 halves: k = (e>>2)*16 + khi*4 + (e&3)
// map==1: contiguous 8:            k = khi*8 + e
__device__ inline int korder2(int map, int khi, int e) {
    return map ? ((khi << 3) | e)
               : (((e >> 2) << 4) | (khi << 2) | (e & 3));
}

// spike (m,b) -> byte index into i8 B-fragment buffer (frag = K=64: two K=32 halves)
__device__ inline size_t sfrag3_idx(int m, int b, int bm) {
    int kt = m >> 6, kl = m & 63, half = kl >> 5, klh = kl & 31;
    int khi, e;
    if (bm) { khi = klh >> 3; e = klh & 7; }
    else    { khi = (klh >> 2) & 3; e = (klh & 3) | (((klh >> 4) & 1) << 2); }
    return ((size_t)(kt * 4 + (b >> 4)) * 64 + khi * 16 + (b & 15)) * 16 + half * 8 + e;
}

// ---------------- layout probe for i8 MFMA: combo[3] = am | bm<<1 | dmap<<2 ----------------
// A[i][k], B[k][j] small ints; i32 accumulation exact; probe self-verifies lane maps.
__global__ void kernProbe3(int* __restrict__ combo_out) {
    int l = threadIdx.x;
    int khi = l >> 4, c = l & 15;
    int best = -1;
    for (int cb = 0; cb < 8; ++cb) {
        int am = cb & 1, bm = (cb >> 1) & 1, dmap = (cb >> 2) & 1;
        unsigned long long au = 0, bu = 0;
        #pragma unroll
        for (int e = 0; e < 8; ++e) {
            int ka = korder2(am, khi, e);
            int kb = korder2(bm, khi, e);
            int aval = ((c * 5 + ka * 3) % 51) - 25;
            int bval = ((kb * 7 + c * 13) % 51) - 25;
            au |= (unsigned long long)(unsigned char)(char)aval << (8 * e);
            bu |= (unsigned long long)(unsigned char)(char)bval << (8 * e);
        }
        i4v d = {0, 0, 0, 0};
        d = __builtin_amdgcn_mfma_i32_16x16x32_i8((long)au, (long)bu, d, 0, 0, 0);
        bool ok = true;
        #pragma unroll
        for (int r = 0; r < 4; ++r) {
            int q = (l >> 4) * 4 + r;
            int di = dmap ? c : q;
            int dj = dmap ? q : c;
            int ref = 0;
            for (int k = 0; k < 32; ++k)
                ref += (((di * 5 + k * 3) % 51) - 25) * (((k * 7 + dj * 13) % 51) - 25);
            ok = ok && (d[r] == ref);
        }
        unsigned long long m = __ballot(ok);
        if (m == ~0ull && best < 0) best = cb;
    }
    if (l == 0) combo_out[3] = (best < 0) ? 0 : best;
}

// ---------------- global max|W| then scale exponent ----------------
__global__ __launch_bounds__(256) void kernS(const float* __restrict__ W, unsigned* __restrict__ mx) {
    unsigned m = 0;
    for (size_t i = (size_t)blockIdx.x * blockDim.x + threadIdx.x;
         i < (size_t)N_NEUR * N_NEUR; i += (size_t)gridDim.x * blockDim.x)
        m = max(m, __float_as_uint(fabsf(W[i])));
    for (int off = 32; off > 0; off >>= 1)
        m = max(m, (unsigned)__shfl_down((int)m, off, 64));
    if ((threadIdx.x & 63) == 0) atomicMax(mx, m);
}

__global__ void kernSc(const unsigned* __restrict__ mx, int* __restrict__ combo) {
    float m = __uint_as_float(*mx);
    int s = 26;
    if (m > 1e-30f) {
        s = (int)floorf(log2f(8.3e6f / m));
        while (ldexpf(m, s) > 8.3e6f) --s;
        while (ldexpf(m, s + 1) <= 8.3e6f) ++s;
    }
    combo[2] = s;
}

// ---------------- pack W into 3 i8 digit planes, A-fragment order ----------------
// Wf layout (bytes): frag(nt, kt64, digit) at ((nt*64+kt64)*3+digit)*1024 + lane*16,
// lane's 16 bytes = [K=32 half0: e 0..7 | half1: e 0..7] per korder.
__global__ __launch_bounds__(256) void kernP3(const float* __restrict__ W,
                                              char* __restrict__ Wf,
                                              const int* __restrict__ combo_p) {
    const int am = combo_p[3] & 1;
    const int sc = combo_p[2];
    const int nt = blockIdx.x;                 // 0..255
    const int lane = threadIdx.x & 63, wv = threadIdx.x >> 6;
    const int khi = lane >> 4, ai = lane & 15;
    const float* wrow = W + (size_t)(nt * 16 + ai) * N_NEUR;
    for (int kt = wv; kt < 64; kt += 4) {
        unsigned long long p0[2] = {0, 0}, p1[2] = {0, 0}, p2[2] = {0, 0};
        #pragma unroll
        for (int half = 0; half < 2; ++half) {
            #pragma unroll
            for (int e = 0; e < 8; ++e) {
                int kk = kt * 64 + half * 32 + korder2(am, khi, e);
                float w = wrow[kk];
                int q = (int)rintf(ldexpf(w, sc));
                int b0 = (int)(char)(q & 255);  int r1 = (q - b0) >> 8;
                int b1 = (int)(char)(r1 & 255); int b2 = (r1 - b1) >> 8;
                p0[half] |= (unsigned long long)(unsigned char)(char)b0 << (8 * e);
                p1[half] |= (unsigned long long)(unsigned char)(char)b1 << (8 * e);
                p2[half] |= (unsigned long long)(unsigned char)(char)b2 << (8 * e);
            }
        }
        size_t base = (((size_t)nt * 64 + kt) * 3) * 1024 + (size_t)lane * 16;
        *(l2v*)(Wf + base)        = (l2v){(long)p0[0], (long)p0[1]};
        *(l2v*)(Wf + base + 1024) = (l2v){(long)p1[0], (long)p1[1]};
        *(l2v*)(Wf + base + 2048) = (l2v){(long)p2[0], (long)p2[1]};
    }
}

// ---------------- t=0 init (i8 path) ----------------
__global__ __launch_bounds__(256) void kernI3(const float* __restrict__ x,
                                              const float* __restrict__ Win,
                                              double* __restrict__ vr,
                                              char* __restrict__ sf,
                                              float* __restrict__ sT,
                                              const int* __restrict__ combo_p) {
    const int bm = (combo_p[3] >> 1) & 1;
    int idx = blockIdx.x * 256 + threadIdx.x;
    int b = idx & 63, n = idx >> 6;
    double v = (double)x[b * T_STEPS] * (double)Win[n];
    bool sp = (v >= 1.0);
    vr[idx] = sp ? 0.0 : v;
    sT[idx] = sp ? 1.0f : 0.0f;
    sf[sfrag3_idx(n, b, bm)] = sp ? (char)1 : (char)0;
}

// ---------------- shared GEMM + reservoir-LIF body (i8), 1024 threads / 16 waves ----------------
__device__ __forceinline__ void gemm_lif_i8(int bid, int tid, double (*lbuf)[1024],
                                            const char* __restrict__ Wf,
                                            const char* __restrict__ sfp,
                                            const float* __restrict__ x,
                                            const float* __restrict__ Win,
                                            double* __restrict__ vr,
                                            char* __restrict__ sfc,
                                            float* __restrict__ sTc,
                                            int comboI, int sc, int t) {
    const int wave = tid >> 6, lane = tid & 63;
    const int bm = (comboI >> 1) & 1, dmap = (comboI >> 2) & 1;

    i4v acc[4][3];
    #pragma unroll
    for (int i = 0; i < 4; ++i)
        #pragma unroll
        for (int j = 0; j < 3; ++j)
            acc[i][j] = (i4v){0, 0, 0, 0};

    const char* ap = Wf  + (((size_t)bid * 64 + (size_t)wave * 4) * 3) * 1024 + (size_t)lane * 16;
    const char* bp = sfp + ((size_t)wave * 4 * 4) * 1024 + (size_t)lane * 16;

    #pragma unroll 2
    for (int kf = 0; kf < 4; ++kf) {
        l2v a[3], b[4];
        #pragma unroll
        for (int s = 0; s < 3; ++s) a[s] = *(const l2v*)(ap + s * 1024);
        #pragma unroll
        for (int bt = 0; bt < 4; ++bt) b[bt] = *(const l2v*)(bp + bt * 1024);
        #pragma unroll
        for (int bt = 0; bt < 4; ++bt) {
            #pragma unroll
            for (int s = 0; s < 3; ++s) {
                acc[bt][s] = __builtin_amdgcn_mfma_i32_16x16x32_i8(a[s][0], b[bt][0], acc[bt][s], 0, 0, 0);
                acc[bt][s] = __builtin_amdgcn_mfma_i32_16x16x32_i8(a[s][1], b[bt][1], acc[bt][s], 0, 0, 0);
            }
        }
        ap += 3072;
        bp += 4096;
    }

    const double inv = ldexp(1.0, -sc);
    double vals[4][4];
    int idxs[4][4];
    #pragma unroll
    for (int bt = 0; bt < 4; ++bt) {
        #pragma unroll
        for (int r = 0; r < 4; ++r) {
            long long qq = (long long)acc[bt][2][r] * 65536LL
                         + (long long)acc[bt][1][r] * 256LL
                         + (long long)acc[bt][0][r];
            vals[bt][r] = inv * (double)qq;
            int q = (lane >> 4) * 4 + r;
            int di = dmap ? (lane & 15) : q;
            int dj = dmap ? q : (lane & 15);
            idxs[bt][r] = di * 64 + bt * 16 + dj;
        }
    }
    if (wave < 8) {
        #pragma unroll
        for (int bt = 0; bt < 4; ++bt)
            #pragma unroll
            for (int r = 0; r < 4; ++r)
                lbuf[wave][idxs[bt][r]] = vals[bt][r];
    }
    __syncthreads();
    if (wave >= 8) {
        #pragma unroll
        for (int bt = 0; bt < 4; ++bt)
            #pragma unroll
            for (int r = 0; r < 4; ++r)
                lbuf[wave - 8][idxs[bt][r]] += vals[bt][r];
    }
    __syncthreads();

    // reservoir LIF (one output per thread)
    {
        int n = bid * 16 + (tid >> 6), b = tid & 63;
        size_t gidx = (size_t)n * 64 + b;
        double cur = lbuf[0][tid] + lbuf[1][tid] + lbuf[2][tid] + lbuf[3][tid]
                   + lbuf[4][tid] + lbuf[5][tid] + lbuf[6][tid] + lbuf[7][tid]
                   + (double)x[b * T_STEPS + t] * (double)Win[n];
        double v = 0.9 * vr[gidx] + cur;
        bool sp = (v >= 1.0);
        vr[gidx] = sp ? 0.0 : v;
        sTc[gidx] = sp ? 1.0f : 0.0f;
        sfc[sfrag3_idx(n, b, bm)] = sp ? (char)1 : (char)0;
    }
}

// ---------------- persistent coop loop (i8): 256 blocks x 1024 threads ----------------
__global__ __launch_bounds__(1024, 4) void kernLoop3(const char* __restrict__ Wf,
                                                     char* __restrict__ sf0,
                                                     char* __restrict__ sf1,
                                                     const float* __restrict__ x,
                                                     const float* __restrict__ Win,
                                                     double* __restrict__ vr,
                                                     float* __restrict__ sTa,
                                                     float* __restrict__ sTb,
                                                     const float* __restrict__ Wout,
                                                     double* __restrict__ vc,
                                                     double* __restrict__ counts,
                                                     double* __restrict__ P0,
                                                     double* __restrict__ P1,
                                                     const int* __restrict__ combo_p) {
    __shared__ double lbuf[8][1024];
    __shared__ double red[16][N_CLS];
    cg::grid_group grid = cg::this_grid();
    const int bid = blockIdx.x, tid = threadIdx.x;
    const int wave = tid >> 6, lane = tid & 63;
    const int comboI = combo_p[3];
    const int sc = combo_p[2];

    for (int t = 1; t < T_STEPS; ++t) {
        const char* sfp = (t & 1) ? sf0 : sf1;
        char*       sfc = (t & 1) ? sf1 : sf0;
        float*       sTc = (t & 1) ? sTb : sTa;
        const float* sTp = (t & 1) ? sTa : sTb;
        double* Pcur  = (t & 1) ? P1 : P0;
        double* Pprev = (t & 1) ? P0 : P1;

        gemm_lif_i8(bid, tid, lbuf, Wf, sfp, x, Win, vr, sfc, sTc, comboI, sc, t);

        // ---- classifier partial for s_{t-1}: batch bid>>2, m-range (bid&3)*1024 ----
        {
            int b2 = bid >> 2;
            int m = ((bid & 3) << 10) + tid;
            float s = sTp[(size_t)m * B_SZ + b2];
            double part[N_CLS];
            if (s != 0.0f) {
                #pragma unroll
                for (int c = 0; c < N_CLS; ++c)
                    part[c] = (double)Wout[c * N_NEUR + m];
            } else {
                #pragma unroll
                for (int c = 0; c < N_CLS; ++c) part[c] = 0.0;
            }
            #pragma unroll
            for (int c = 0; c < N_CLS; ++c) {
                double v = part[c];
                for (int off = 32; off > 0; off >>= 1)
                    v += __shfl_down(v, off, 64);
                if (lane == 0) red[wave][c] = v;
            }
            __syncthreads();
            if (tid < N_CLS) {
                double tot = 0.0;
                #pragma unroll
                for (int wv = 0; wv < 16; ++wv) tot += red[wv][tid];
                atomicAdd(&Pcur[b2 * N_CLS + tid], tot);
            }
        }

        // ---- classifier LIF for s_{t-2} from Pprev ----
        if (bid < B_SZ && t >= 2 && tid < N_CLS) {
            double tot = Pprev[bid * N_CLS + tid];
            double v = 0.9 * vc[bid * N_CLS + tid] + tot;
            bool sp = (v >= 1.0);
            vc[bid * N_CLS + tid] = sp ? 0.0 : v;
            if (sp) counts[bid * N_CLS + tid] += 1.0;
            Pprev[bid * N_CLS + tid] = 0.0;
        }

        __threadfence();
        grid.sync();
    }
}

// ---------------- per-step fallback (i8): 320 blocks x 1024 threads ----------------
__global__ __launch_bounds__(1024, 4) void kernStep3(const char* __restrict__ Wf,
                                                     const char* __restrict__ sfp,
                                                     const float* __restrict__ x,
                                                     const float* __restrict__ Win,
                                                     double* __restrict__ vr,
                                                     char* __restrict__ sfc,
                                                     float* __restrict__ sTc,
                                                     const float* __restrict__ sTp,
                                                     const float* __restrict__ Wout,
                                                     double* __restrict__ vc,
                                                     double* __restrict__ counts,
                                                     const int* __restrict__ combo_p,
                                                     int t) {
    __shared__ double lbuf[8][1024];
    __shared__ double red[16][N_CLS];
    const int bid = blockIdx.x, tid = threadIdx.x;
    const int wave = tid >> 6, lane = tid & 63;

    if (bid >= 256) {
        // classifier for step t-1, batch b
        const int b = bid - 256;
        double part[N_CLS];
        #pragma unroll
        for (int c = 0; c < N_CLS; ++c) part[c] = 0.0;
        for (int m = tid; m < N_NEUR; m += 1024) {
            double s = (double)sTp[(size_t)m * B_SZ + b];
            #pragma unroll
            for (int c = 0; c < N_CLS; ++c)
                part[c] = fma(s, (double)Wout[c * N_NEUR + m], part[c]);
        }
        #pragma unroll
        for (int c = 0; c < N_CLS; ++c) {
            double v = part[c];
            for (int off = 32; off > 0; off >>= 1)
                v += __shfl_down(v, off, 64);
            if (lane == 0) red[wave][c] = v;
        }
        __syncthreads();
        if (tid < N_CLS) {
            double tot = 0.0;
            #pragma unroll
            for (int wv = 0; wv < 16; ++wv) tot += red[wv][tid];
            double v = 0.9 * vc[b * N_CLS + tid] + tot;
            bool sp = (v >= 1.0);
            vc[b * N_CLS + tid] = sp ? 0.0 : v;
            if (sp) counts[b * N_CLS + tid] += 1.0;
        }
        return;
    }
    gemm_lif_i8(bid, tid, lbuf, Wf, sfp, x, Win, vr, sfc, sTc, combo_p[3], combo_p[2], t);
}

// ---------------- epilogue: vc update for s_126 (from Pp) then s_127 (direct dot) ----------------
__global__ __launch_bounds__(256) void kernC2(const float* __restrict__ sT,
                                              const float* __restrict__ Wout,
                                              double* __restrict__ vc,
                                              double* __restrict__ counts,
                                              const double* __restrict__ Pp) {
    int b = blockIdx.x;
    int tid = threadIdx.x;
    if (tid < N_CLS) {
        double v = 0.9 * vc[b * N_CLS + tid] + Pp[b * N_CLS + tid];
        bool sp = (v >= 1.0);
        vc[b * N_CLS + tid] = sp ? 0.0 : v;
        if (sp) counts[b * N_CLS + tid] += 1.0;
    }
    double part[N_CLS];
    #pragma unroll
    for (int c = 0; c < N_CLS; ++c) part[c] = 0.0;
    for (int m = tid; m < N_NEUR; m += 256) {
        double s = (double)sT[(size_t)m * B_SZ + b];
        #pragma unroll
        for (int c = 0; c < N_CLS; ++c)
            part[c] = fma(s, (double)Wout[c * N_NEUR + m], part[c]);
    }
    __shared__ double red[4][N_CLS];
    int lane = tid & 63, wv = tid >> 6;
    #pragma unroll
    for (int c = 0; c < N_CLS; ++c) {
        double v = part[c];
        for (int off = 32; off > 0; off >>= 1)
            v += __shfl_down(v, off, 64);
        if (lane == 0) red[wv][c] = v;
    }
    __syncthreads();
    if (tid < N_CLS) {
        double tot = red[0][tid] + red[1][tid] + red[2][tid] + red[3][tid];
        double v = 0.9 * vc[b * N_CLS + tid] + tot;
        bool sp = (v >= 1.0);
        vc[b * N_CLS + tid] = sp ? 0.0 : v;
        if (sp) counts[b * N_CLS + tid] += 1.0;
    }
}

// ---------------- standalone classifier (final step, fallback path) ----------------
__global__ __launch_bounds__(256) void kernC(const float* __restrict__ sT,
                                             const float* __restrict__ Wout,
                                             double* __restrict__ vc,
                                             double* __restrict__ counts) {
    int b = blockIdx.x;
    int tid = threadIdx.x;
    double part[N_CLS];
    #pragma unroll
    for (int c = 0; c < N_CLS; ++c) part[c] = 0.0;
    for (int m = tid; m < N_NEUR; m += 256) {
        double s = (double)sT[(size_t)m * B_SZ + b];
        #pragma unroll
        for (int c = 0; c < N_CLS; ++c)
            part[c] = fma(s, (double)Wout[c * N_NEUR + m], part[c]);
    }
    __shared__ double red[4][N_CLS];
    int lane = tid & 63, wv = tid >> 6;
    #pragma unroll
    for (int c = 0; c < N_CLS; ++c) {
        double v = part[c];
        for (int off = 32; off > 0; off >>= 1)
            v += __shfl_down(v, off, 64);
        if (lane == 0) red[wv][c] = v;
    }
    __syncthreads();
    if (tid < N_CLS) {
        double tot = red[0][tid] + red[1][tid] + red[2][tid] + red[3][tid];
        double v = 0.9 * vc[b * N_CLS + tid] + tot;
        bool sp = (v >= 1.0);
        vc[b * N_CLS + tid] = sp ? 0.0 : v;
        if (sp) counts[b * N_CLS + tid] += 1.0;
    }
}

__global__ void kernD(const double* __restrict__ counts, float* __restrict__ out) {
    int i = blockIdx.x * blockDim.x + threadIdx.x;
    if (i < B_SZ * N_CLS) out[i] = (float)counts[i];
}

// =====================================================================================
// f64 fallback path (verified) — used when ws too small for the i8 planes.
// =====================================================================================

__global__ void kernProbe(int* __restrict__ combo_out) {
    int l = threadIdx.x;
    int best = -1;
    for (int c = 0; c < 16; ++c) {
        int amap = c & 1, bmap = (c >> 1) & 1, dmap = (c >> 2) & 3;
        int ai = amap ? (l >> 2) : (l & 15);
        int ak = amap ? (l & 3)  : (l >> 4);
        int bk = bmap ? (l & 3)  : (l >> 4);
        int bj = bmap ? (l >> 2) : (l & 15);
        double a = (double)(ai * 4 + ak + 1);
        double b = (double)(bk * 16 + bj + 1);
        d4v d = {0.0, 0.0, 0.0, 0.0};
        d = __builtin_amdgcn_mfma_f64_16x16x4f64(a, b, d, 0, 0, 0);
        bool ok = true;
        #pragma unroll
        for (int r = 0; r < 4; ++r) {
            int di, dj;
            if      (dmap == 0) { di = 4 * (l >> 4) + r; dj = l & 15; }
            else if (dmap == 1) { di = l & 15; dj = 4 * (l >> 4) + r; }
            else if (dmap == 2) { di = (l >> 4) + 4 * r; dj = l & 15; }
            else                { di = l & 15; dj = (l >> 4) + 4 * r; }
            double ref = 0.0;
            for (int k = 0; k < 4; ++k)
                ref += (double)(di * 4 + k + 1) * (double)(k * 16 + dj + 1);
            ok = ok && (d[r] == ref);
        }
        unsigned long long m = __ballot(ok);
        if (m == ~0ull && best < 0) best = c;
    }
    if (l == 0) combo_out[0] = (best < 0) ? 0 : best;
}

__global__ __launch_bounds__(256) void kernP(const float* __restrict__ W,
                                             float* __restrict__ Wf,
                                             const int* __restrict__ combo_p) {
    const int combo = combo_p[0];
    const int amap = combo & 1;
    const int stripe = blockIdx.x;
    const int lane = threadIdx.x & 63;
    const int ai = amap ? (lane >> 2) : (lane & 15);
    const int ak = amap ? (lane & 3)  : (lane >> 4);
    const size_t nrow = (size_t)(stripe * 16 + ai) * N_NEUR;
    for (int q = threadIdx.x >> 6; q < 1024; q += 4)
        Wf[((size_t)stripe * 1024 + q) * 64 + lane] = W[nrow + 4 * q + ak];
}

__global__ __launch_bounds__(256) void kernI(const float* __restrict__ x,
                                             const float* __restrict__ Win,
                                             double* __restrict__ vr,
                                             float* __restrict__ sf,
                                             float* __restrict__ sT) {
    int idx = blockIdx.x * 256 + threadIdx.x;
    int b = idx & 63, n = idx >> 6;
    double v = (double)x[b * T_STEPS] * (double)Win[n];
    bool sp = (v >= 1.0);
    vr[idx] = sp ? 0.0 : v;
    float s = sp ? 1.0f : 0.0f;
    sT[idx] = s;
    sf[(size_t)(((n >> 2) * 4 + (b >> 4)) * 64) + (n & 3) * 16 + (b & 15)] = s;
}

template<bool USEWF>
__global__ __launch_bounds__(1024) void kernAB(const float* __restrict__ Wsrc,
                                               const float* __restrict__ sfp,
                                               const float* __restrict__ x,
                                               const float* __restrict__ Win,
                                               double* __restrict__ vr,
                                               float* __restrict__ sfc,
                                               float* __restrict__ sTc,
                                               const float* __restrict__ sTp,
                                               const float* __restrict__ Wout,
                                               double* __restrict__ vc,
                                               double* __restrict__ counts,
                                               const int* __restrict__ combo_p,
                                               int t) {
    __shared__ double lbuf[4][16 * 64];
    __shared__ double red[16][N_CLS];
    const int tid  = threadIdx.x;
    const int wave = tid >> 6, lane = tid & 63;

    if (blockIdx.x >= 256) {
        const int b = blockIdx.x - 256;
        double part[N_CLS];
        #pragma unroll
        for (int c = 0; c < N_CLS; ++c) part[c] = 0.0;
        for (int m = tid; m < N_NEUR; m += 1024) {
            double s = (double)sTp[(size_t)m * B_SZ + b];
            #pragma unroll
            for (int c = 0; c < N_CLS; ++c)
                part[c] = fma(s, (double)Wout[c * N_NEUR + m], part[c]);
        }
        #pragma unroll
        for (int c = 0; c < N_CLS; ++c) {
            double v = part[c];
            for (int off = 32; off > 0; off >>= 1)
                v += __shfl_down(v, off, 64);
            if (lane == 0) red[wave][c] = v;
        }
        __syncthreads();
        if (tid < N_CLS) {
            double tot = 0.0;
            #pragma unroll
            for (int wv = 0; wv < 16; ++wv) tot += red[wv][tid];
            double v = 0.9 * vc[b * N_CLS + tid] + tot;
            bool sp = (v >= 1.0);
            vc[b * N_CLS + tid] = sp ? 0.0 : v;
            if (sp) counts[b * N_CLS + tid] += 1.0;
        }
        return;
    }

    const int wb = wave & 3, wq = wave >> 2;
    const int gn0 = blockIdx.x * 16;
    const int combo = combo_p[0];
    const int amap = combo & 1, bmap = (combo >> 1) & 1, dmap = (combo >> 2) & 3;
    const int bk = bmap ? (lane & 3)  : (lane >> 4);
    const int bj = bmap ? (lane >> 2) : (lane & 15);

    d4v acc = {0.0, 0.0, 0.0, 0.0};
    const int q0 = wq * 256;
    const float* bp = sfp + (size_t)(q0 * 4 + wb) * 64 + bk * 16 + bj;

    if (USEWF) {
        const float* ap = Wsrc + ((size_t)blockIdx.x * 1024 + q0) * 64 + lane;
        for (int blk = 0; blk < 64; ++blk) {
            #pragma unroll
            for (int u = 0; u < 4; ++u) {
                double a  = (double)ap[u * 64];
                double bv = (double)bp[u * 256];
                acc = __builtin_amdgcn_mfma_f64_16x16x4f64(a, bv, acc, 0, 0, 0);
            }
            ap += 256;
            bp += 1024;
        }
    } else {
        const int ai = amap ? (lane >> 2) : (lane & 15);
        const int ak = amap ? (lane & 3)  : (lane >> 4);
        #pragma unroll 4
        for (int q = 0; q < 256; ++q) {
            double a  = (double)Wsrc[(size_t)(gn0 + ai) * N_NEUR + 4 * (q0 + q) + ak];
            double bv = (double)bp[(size_t)q * 256];
            acc = __builtin_amdgcn_mfma_f64_16x16x4f64(a, bv, acc, 0, 0, 0);
        }
    }

    {
        const int jb = 16 * wb;
        #pragma unroll
        for (int r = 0; r < 4; ++r) {
            int di, dj;
            if      (dmap == 0) { di = 4 * (lane >> 4) + r; dj = lane & 15; }
            else if (dmap == 1) { di = lane & 15; dj = 4 * (lane >> 4) + r; }
            else if (dmap == 2) { di = (lane >> 4) + 4 * r; dj = lane & 15; }
            else                { di = lane & 15; dj = (lane >> 4) + 4 * r; }
            lbuf[wq][di * 64 + jb + dj] = acc[r];
        }
    }
    __syncthreads();

    int nl = tid >> 6, b = tid & 63;
    int n = gn0 + nl;
    size_t gidx = (size_t)n * 64 + b;
    double cur = lbuf[0][tid] + lbuf[1][tid] + lbuf[2][tid] + lbuf[3][tid]
               + (double)x[b * T_STEPS + t] * (double)Win[n];
    double v = 0.9 * vr[gidx] + cur;
    bool sp = (v >= 1.0);
    vr[gidx] = sp ? 0.0 : v;
    float s = sp ? 1.0f : 0.0f;
    sTc[gidx] = s;
    sfc[(size_t)(((n >> 2) * 4 + (b >> 4)) * 64) + (n & 3) * 16 + (b & 15)] = s;
}

extern "C" void kernel_launch(void* const* d_in, const int* in_sizes, int n_in,
                              void* d_out, int out_size, void* d_ws, size_t ws_size,
                              hipStream_t stream) {
    const float* x    = (const float*)d_in[0];
    const float* Win  = (const float*)d_in[1];
    const float* Wres = (const float*)d_in[2];
    const float* Wout = (const float*)d_in[3];
    float* out = (float*)d_out;

    const size_t NB = (size_t)B_SZ * N_NEUR;
    char* w = (char*)d_ws;
    double* vr     = (double*)w;  w += NB * sizeof(double);
    float*  sTa    = (float*)w;   w += NB * sizeof(float);
    float*  sTb    = (float*)w;   w += NB * sizeof(float);
    float*  sf0    = (float*)w;   w += NB * sizeof(float);   // i8 path uses first 256KB as char
    float*  sf1    = (float*)w;   w += NB * sizeof(float);
    double* vc     = (double*)w;  w += (size_t)B_SZ * N_CLS * sizeof(double);
    double* counts = (double*)w;  w += (size_t)B_SZ * N_CLS * sizeof(double);
    double* P0     = (double*)w;  w += (size_t)B_SZ * N_CLS * sizeof(double);
    double* P1     = (double*)w;  w += (size_t)B_SZ * N_CLS * sizeof(double);
    int*    combo  = (int*)w;     w += 256;
    float*  Wf     = (float*)w;   // f64 path: 64 MB packed W; i8 path: 48 MB digit planes

    size_t fixed = (size_t)(w - (char*)d_ws);
    bool use_i8 = (ws_size >= fixed + 3ull * N_NEUR * N_NEUR);
    bool use_wf = (ws_size >= fixed + (size_t)N_NEUR * N_NEUR * sizeof(float));

    hipMemsetAsync(vc, 0, 4ull * B_SZ * N_CLS * sizeof(double), stream);   // vc, counts, P0, P1
    hipMemsetAsync(combo, 0, 256, stream);

    if (use_i8) {
        char* Wfi  = (char*)Wf;
        char* sf0c = (char*)sf0;
        char* sf1c = (char*)sf1;
        unsigned* mx = (unsigned*)(combo + 8);

        kernProbe3<<<dim3(1), 64, 0, stream>>>(combo);
        kernS<<<dim3(1024), 256, 0, stream>>>(Wres, mx);
        kernSc<<<dim3(1), 1, 0, stream>>>(mx, combo);
        kernP3<<<dim3(256), 256, 0, stream>>>(Wres, Wfi, combo);
        kernI3<<<dim3(NB / 256), 256, 0, stream>>>(x, Win, vr, sf0c, sTa, combo);

        int maxb = 0;
        hipError_t occ_err = hipOccupancyMaxActiveBlocksPerMultiprocessor(&maxb, kernLoop3, 1024, 0);
        bool coop = (occ_err == hipSuccess) && (maxb >= 1);

        if (coop) {
            void* kargs[] = {(void*)&Wfi, (void*)&sf0c, (void*)&sf1c, (void*)&x, (void*)&Win,
                             (void*)&vr, (void*)&sTa, (void*)&sTb, (void*)&Wout, (void*)&vc,
                             (void*)&counts, (void*)&P0, (void*)&P1, (void*)&combo};
            hipError_t le = hipLaunchCooperativeKernel((const void*)kernLoop3, dim3(256), dim3(1024),
                                                       kargs, 0, stream);
            coop = (le == hipSuccess);
        }
        if (coop) {
            kernC2<<<dim3(B_SZ), 256, 0, stream>>>(sTb, Wout, vc, counts, P1);
        } else {
            for (int t = 1; t < T_STEPS; ++t) {
                const char* sfp = (t & 1) ? sf0c : sf1c;
                char*       sfc = (t & 1) ? sf1c : sf0c;
                float*       sTc = (t & 1) ? sTb : sTa;
                const float* sTp = (t & 1) ? sTa : sTb;
                kernStep3<<<dim3(320), 1024, 0, stream>>>(Wfi, sfp, x, Win, vr, sfc, sTc, sTp,
                                                          Wout, vc, counts, combo, t);
            }
            kernC<<<dim3(B_SZ), 256, 0, stream>>>(sTb, Wout, vc, counts);
        }
        kernD<<<dim3(3), 256, 0, stream>>>(counts, out);
        return;
    }

    kernProbe<<<dim3(1), 64, 0, stream>>>(combo);
    if (use_wf)
        kernP<<<dim3(256), 256, 0, stream>>>(Wres, Wf, combo);

    kernI<<<dim3(NB / 256), 256, 0, stream>>>(x, Win, vr, sf0, sTa);
    for (int t = 1; t < T_STEPS; ++t) {
        const float* sfp = (t & 1) ? sf0 : sf1;
        float*       sfc = (t & 1) ? sf1 : sf0;
        float*       sTc = (t & 1) ? sTb : sTa;
        const float* sTp = (t & 1) ? sTa : sTb;
        if (use_wf)
            kernAB<true><<<dim3(320), 1024, 0, stream>>>(Wf, sfp, x, Win, vr, sfc, sTc, sTp,
                                                         Wout, vc, counts, combo, t);
        else
            kernAB<false><<<dim3(320), 1024, 0, stream>>>(Wres, sfp, x, Win, vr, sfc, sTc, sTp,
                                                          Wout, vc, counts, combo, t);
    }
    kernC<<<dim3(B_SZ), 256, 0, stream>>>(sTb, Wout, vc, counts);
    kernD<<<dim3(3), 256, 0, stream>>>(counts, out);
}